// Round 2
// baseline (81.638 us; speedup 1.0000x reference)
//
#include <hip/hip_runtime.h>
#include <math.h>

// Problem constants (fixed by reference: inp (4,16,32,32) f32, weight (64,144) f32)
constexpr int F_IN   = 144;   // 16 ch * 9 taps
constexpr int F_OUT  = 64;
constexpr int H_IMG  = 32;
constexpr int W_IMG  = 32;
constexpr int NPIX   = 4 * H_IMG * W_IMG;  // 4096
constexpr int PPB    = 8;                  // pixels per block (1 wave each)
constexpr int NTHR   = PPB * 64;           // 512
constexpr int WPT    = F_IN / PPB;         // 18 f-slots per wave in quant phase
#define MAX_SPIKE 100.0f

// ---------------------------------------------------------------------------
// ROUND-7 CHANGE (resubmit after container flake): fuse weight quantization
// INTO the spike kernel.
// Evidence: round-6 (tanh->tanhf, predicted -45us on quant) moved dur_us by
// only 0.6us -> the "quant=52us" fit was wrong; quant is a tiny 36-block
// launch whose cost is launch latency + stream dependency + a 36KB global
// round-trip. Fusing removes: 1 kernel launch, the inter-kernel dependency,
// the wqT global write+read, and ALL workspace usage. Added cost per spike
// block: 18 tanhf + ~6 VALU per thread (~1-1.5us), since every block needed
// to pull 36KB of weights through L2 into LDS anyway (wqT staging before,
// raw w now -- same bytes).
//
// Quant math is op-for-op identical to the validated rounds (bit-exact):
//   alpha = tanhf(max|w|)  (tanhf monotone on |w| => == max|tanhf(w)|)
//   x = tanhf(w)/alpha; clip; *127; rintf (half-to-even); *alpha/127.
//
// Quant thread mapping: lane = output channel o, wave = 18-wide f slice.
//   read  w[lane*144 + f]        : 576B lane stride, ~2 L1 lines/thread (L2-hot)
//   write wql[f*64 + lane]       : 64 lanes span banks 0..31 twice -> 2-way, free
// ---------------------------------------------------------------------------
__global__ __launch_bounds__(NTHR, 4) void spike_conv_fused(
    const float* __restrict__ inp,   // (4,16,32,32)
    const float* __restrict__ w,     // (64,144) RAW weights
    float* __restrict__ out)         // (4,64,32,32)
{
#pragma clang fp contract(off)
    __shared__ __align__(16) float wql[F_IN * F_OUT];          // 36 KB
    __shared__ __align__(16) unsigned long long kr[PPB][F_IN]; // 9 KB
    __shared__ float sv[PPB][F_IN + 1];                        // 4.5 KB
    __shared__ float wred[PPB];                                // 32 B

    const int tid  = threadIdx.x;
    const int lane = tid & 63;
    const int wv_i = tid >> 6;                   // wave id = pixel-in-block
    const int p    = blockIdx.x * PPB + wv_i;    // pixel id
    const int b    = p >> 10;
    const int l    = p & 1023;
    const int h    = l >> 5;
    const int wcol = l & 31;

    // ---- A: issue raw-weight loads early (latency hides under patch+sort) ----
    // This thread owns (o = lane, f = fbase .. fbase+17). 8B-aligned float2s.
    const int fbase = wv_i * WPT;
    float wreg[WPT];
    {
        const float2* g2 = (const float2*)(w + lane * F_IN + fbase);
#pragma unroll
        for (int k2 = 0; k2 < WPT / 2; ++k2) {
            const float2 v = g2[k2];
            wreg[2 * k2]     = v.x;
            wreg[2 * k2 + 1] = v.y;
        }
    }

    // ---- B: stage patch, build keys (feature f = c*9 + kh*3 + kw) ----
    float v0f, v1f, v2f;
    unsigned long long key0, key1, key2;
    {
        int idx[3] = { lane, lane + 64, lane + 128 };
        float vals[3];
        for (int m2 = 0; m2 < 3; ++m2) {
            const int i = idx[m2];
            float v = MAX_SPIKE;
            if (i < F_IN) {
                const int c  = i / 9;
                const int r  = i - c * 9;
                const int kh = r / 3;
                const int kw = r - kh * 3;
                const int hh = h + kh - 1;
                const int ww = wcol + kw - 1;
                float x = 0.f;
                if (hh >= 0 && hh < H_IMG && ww >= 0 && ww < W_IMG)
                    x = inp[((b * 16 + c) * H_IMG + hh) * W_IMG + ww];
                v = (x < 0.1f) ? MAX_SPIKE : x;
                kr[wv_i][i] = ((unsigned long long)__float_as_uint(v) << 8)
                              | (unsigned)i;
            }
            vals[m2] = v;
        }
        v0f = vals[0]; v1f = vals[1]; v2f = vals[2];
        key0 = ((unsigned long long)__float_as_uint(v0f) << 8) | (unsigned)idx[0];
        key1 = ((unsigned long long)__float_as_uint(v1f) << 8) | (unsigned)idx[1];
        key2 = ((unsigned long long)__float_as_uint(v2f) << 8) | (unsigned)idx[2];
        if (lane == 0) sv[wv_i][F_IN] = 1.0f;    // causality sentinel
    }
    // kr/sv wave-private: same-wave DS ordering is in-order -> no barrier.

    // ---- rank sort (keys unique -> strict < == exact stable permutation) ----
    int r0 = 0, r1 = 0, r2 = 0;
    {
        const ulonglong2* ks2 = (const ulonglong2*)&kr[wv_i][0];
#pragma unroll 4
        for (int j = 0; j < F_IN / 2; ++j) {
            const ulonglong2 kk = ks2[j];   // wave-broadcast read: conflict-free
            r0 += (kk.x < key0) + (kk.y < key0);
            r1 += (kk.x < key1) + (kk.y < key1);
            r2 += (kk.x < key2) + (kk.y < key2);
        }
    }

    // ---- scatter sorted values + record-lo (wq LDS row word offset) ----
    {
        unsigned* krlo = (unsigned*)&kr[wv_i][0];   // little-endian: lo at +0
        sv[wv_i][r0] = v0f;  krlo[2 * r0] = (unsigned)lane << 6;
        sv[wv_i][r1] = v1f;  krlo[2 * r1] = (unsigned)(lane + 64) << 6;
        if (lane < F_IN - 128) {
            sv[wv_i][r2] = v2f;  krlo[2 * r2] = (unsigned)(lane + 128) << 6;
        }
    }

    // ---- record-hi = bits of next sorted value ----
    {
        unsigned* krhi = (unsigned*)&kr[wv_i][0];
        for (int k = lane; k < F_IN; k += 64)
            krhi[2 * k + 1] = __float_as_uint(sv[wv_i][k + 1]);
    }

    // ---- C: block abs-max of raw weights (alpha = tanhf(max|w|)) ----
    float m = 0.f;
#pragma unroll
    for (int k = 0; k < WPT; ++k) m = fmaxf(m, fabsf(wreg[k]));
    for (int s = 32; s > 0; s >>= 1)
        m = fmaxf(m, __shfl_xor(m, s, 64));
    if (lane == 0) wred[wv_i] = m;
    __syncthreads();                              // barrier 1: wred visible
    float mw = wred[0];
#pragma unroll
    for (int q = 1; q < PPB; ++q) mw = fmaxf(mw, wred[q]);
    const float alpha = tanhf(mw);

    // ---- quantize + transposed write into LDS (2-way banks: free) ----
#pragma unroll
    for (int k = 0; k < WPT; ++k) {
        const float t = tanhf(wreg[k]);
        float x = t / alpha;                       // f32 divide (mirrors np)
        x = fminf(fmaxf(x, -1.f), 1.f) * 127.f;    // clip then *qmax
        const float r = rintf(x);                  // round half-to-even
        wql[(fbase + k) * F_OUT + lane] = r * alpha / 127.f;  // mul then div
    }
    __syncthreads();                              // barrier 2: wql visible

    // ---- batched scan: first valid spike == min ----
    float s   = sv[wv_i][0];
    float ws  = 0.f;
    float iws = 0.f;
    float mn  = MAX_SPIKE;      // masked / never-valid lanes => exactly 100
    bool  done = false;
    const ulonglong2* rec2 = (const ulonglong2*)&kr[wv_i][0];
    for (int k0 = 0; k0 < F_IN; k0 += 8) {
        if (s >= MAX_SPIKE) break;            // sorted: rest contribute 100
        const ulonglong2 ra = rec2[(k0 >> 1) + 0];
        const ulonglong2 rb = rec2[(k0 >> 1) + 1];
        const ulonglong2 rc = rec2[(k0 >> 1) + 2];
        const ulonglong2 rd = rec2[(k0 >> 1) + 3];
        const unsigned long long r8[8] = { ra.x, ra.y, rb.x, rb.y,
                                           rc.x, rc.y, rd.x, rd.y };
        float su[8], nx[8], wsu[8], iwsu[8];
#pragma unroll
        for (int u = 0; u < 8; ++u) {
            su[u] = s;
            nx[u] = __uint_as_float((unsigned)(r8[u] >> 32));
            const float wvv = wql[(unsigned)r8[u] + lane];  // 2-way bank: free
            ws += wvv;
            const float prod = su[u] * wvv;   // separate rounding (no FMA)
            iws += prod;
            wsu[u]  = ws;
            iwsu[u] = iws;
            s = nx[u];
        }
        // wq >= 0 => ws monotone: if last ws of batch < 1 for all lanes, the
        // whole batch is masked (contributes exactly 100) -> skip div/compares.
        if (!__all(wsu[7] < 1.0f)) {
#pragma unroll
            for (int u = 0; u < 8; ++u) {
                const float d = fmaxf(wsu[u] - 1.0f, 1e-10f); // upper clamp never binds
                const float q = iwsu[u] / d;                  // IEEE f32 divide
                const bool valid = (wsu[u] >= 1.0f) & (q >= su[u]) & (q <= nx[u]);
                if (valid & !done) { mn = q; done = true; }
            }
            if (__all(done)) break;           // windows increase: first = min
        }
    }
    out[(b * F_OUT + lane) * 1024 + l] = mn;
}

extern "C" void kernel_launch(void* const* d_in, const int* in_sizes, int n_in,
                              void* d_out, int out_size, void* d_ws, size_t ws_size,
                              hipStream_t stream) {
    const float* inp = (const float*)d_in[0];   // 65536 elems
    const float* w   = (const float*)d_in[1];   // 9216 elems
    float* out = (float*)d_out;                 // 262144 elems
    (void)d_ws; (void)ws_size;                  // workspace no longer used

    spike_conv_fused<<<NPIX / PPB, NTHR, 0, stream>>>(inp, w, out);
}